// Round 7
// baseline (245.287 us; speedup 1.0000x reference)
//
#include <hip/hip_runtime.h>
#include <cstdint>
#include <cstddef>

#define Bn 8
#define Nn 2048
#define Fn 64
#define ALPHA 0.2f
#define CAPR 192   // per-row neighbor capacity; mean 102.4, sd 9.9 -> 9 sigma

typedef __attribute__((ext_vector_type(4))) float f4vec;

__device__ __forceinline__ float elu(float x) { return x > 0.f ? x : __expf(x) - 1.f; }
__device__ __forceinline__ float4 ntload4(const float* p) {
    f4vec v = __builtin_nontemporal_load((const f4vec*)p);
    return make_float4(v.x, v.y, v.z, v.w);
}

// ---------------- k1: h = input@W, f1 = h@a1, f2 = h@a2 (+ zero Dsum/C) ----------------
// 16 rows/block (1024 blocks): one Wl LDS-read feeds 4 FMAs; inr reads are wave-uniform
// broadcasts (free). Wave w owns rows {w, w+4, w+8, w+12}.
__global__ __launch_bounds__(256) void k1_h_f(
        const float* __restrict__ inp, const float* __restrict__ W,
        const float* __restrict__ a1, const float* __restrict__ a2,
        float* __restrict__ h, float* __restrict__ f1, float* __restrict__ f2,
        float* __restrict__ Dsum, float* __restrict__ C) {
    __shared__ float Wl[Fn * Fn];
    __shared__ float inr[16][Fn];
    int t = threadIdx.x;
    // fold the old hipMemsetAsync into the first kernel (one fewer dispatch)
    if (blockIdx.x < 64) Dsum[blockIdx.x * 256 + t] = 0.f;
    else if (blockIdx.x == 64) { C[t] = 0.f; C[t + 256] = 0.f; }
    for (int k = t; k < Fn * Fn; k += 256) Wl[k] = W[k];
    size_t row0 = (size_t)blockIdx.x * 16;
    for (int k = t; k < 16 * Fn; k += 256) inr[k >> 6][k & 63] = inp[row0 * Fn + k];
    __syncthreads();
    int rg = t >> 6, o = t & 63;
    float acc0 = 0.f, acc1 = 0.f, acc2 = 0.f, acc3 = 0.f;
#pragma unroll
    for (int f = 0; f < Fn; ++f) {
        float wf = Wl[f * Fn + o];
        acc0 = fmaf(inr[rg][f],      wf, acc0);
        acc1 = fmaf(inr[rg + 4][f],  wf, acc1);
        acc2 = fmaf(inr[rg + 8][f],  wf, acc2);
        acc3 = fmaf(inr[rg + 12][f], wf, acc3);
    }
    float a1o = a1[o], a2o = a2[o];
    float accs[4] = {acc0, acc1, acc2, acc3};
#pragma unroll
    for (int k = 0; k < 4; ++k) {
        size_t row = row0 + rg + 4 * k;
        h[row * Fn + o] = accs[k];
        float p = accs[k] * a1o;
        float q = accs[k] * a2o;
#pragma unroll
        for (int off = 32; off > 0; off >>= 1) {
            p += __shfl_down(p, off, 64);
            q += __shfl_down(q, off, 64);
        }
        if (o == 0) { f1[row] = p; f2[row] = q; }
    }
}

// ------- k2a: stream adj once -> row-major bit words + column sums Dsum (rank-1, exp-free) -------
// M=0 formulation: softmax max-subtraction cancels exactly; exp args bounded ~e^34, safe in f32.
// grid (Bn, 8 colchunks of 256, 32 rowchunks of 64), block 512; 8 dwordx4 in flight upfront.
__global__ __launch_bounds__(512) void k2a_bits(
        const float* __restrict__ adj, const float* __restrict__ f1,
        const float* __restrict__ f2,
        float* __restrict__ Dsum, unsigned* __restrict__ bitsW) {
    int b = blockIdx.x;
    int j0 = blockIdx.y * 256;
    int cj8 = blockIdx.y * 8;
    int i0 = blockIdx.z * 64;
    int w = threadIdx.x >> 6, lane = threadIdx.x & 63;
    float4 f2v = *(const float4*)&f2[b * Nn + j0 + 4 * lane];
    float vh0 = __expf(f2v.x), vp0 = __expf(ALPHA * f2v.x);
    float vh1 = __expf(f2v.y), vp1 = __expf(ALPHA * f2v.y);
    float vh2 = __expf(f2v.z), vp2 = __expf(ALPHA * f2v.z);
    float vh3 = __expf(f2v.w), vp3 = __expf(ALPHA * f2v.w);
    float s0 = 0.f, s1 = 0.f, s2 = 0.f, s3 = 0.f;
    const float* abase = adj + ((size_t)b * Nn) * Nn + j0 + 4 * lane;
    const float* f1b = f1 + b * Nn;

    float4 av[8]; float fi[8];
#pragma unroll
    for (int q = 0; q < 8; ++q) {
        int r = i0 + w + 8 * q;
        av[q] = ntload4(abase + (size_t)r * Nn);   // zero-reuse stream
        fi[q] = f1b[r];
    }
#pragma unroll
    for (int q = 0; q < 8; ++q) {
        int r = i0 + w + 8 * q;
        float u  = __expf(fi[q]);
        float up = __expf(ALPHA * fi[q]);
        bool n0 = av[q].x != 0.f, n1 = av[q].y != 0.f,
             n2 = av[q].z != 0.f, n3 = av[q].w != 0.f;
        float x0 = fi[q] + f2v.x, x1 = fi[q] + f2v.y,
              x2 = fi[q] + f2v.z, x3 = fi[q] + f2v.w;
        float e0 = x0 > 0.f ? u * vh0 : up * vp0;
        float e1 = x1 > 0.f ? u * vh1 : up * vp1;
        float e2 = x2 > 0.f ? u * vh2 : up * vp2;
        float e3 = x3 > 0.f ? u * vh3 : up * vp3;
        s0 += n0 ? e0 : 1.0f;
        s1 += n1 ? e1 : 1.0f;
        s2 += n2 ? e2 : 1.0f;
        s3 += n3 ? e3 : 1.0f;
        unsigned nib = (unsigned)n0 | ((unsigned)n1 << 1) |
                       ((unsigned)n2 << 2) | ((unsigned)n3 << 3);
        unsigned byt = nib | (((unsigned)__shfl_xor((int)nib, 1, 64)) << 4);
        unsigned h16 = byt | (((unsigned)__shfl_xor((int)byt, 2, 64)) << 8);
        unsigned w32 = h16 | (((unsigned)__shfl_xor((int)h16, 4, 64)) << 16);
        if ((lane & 7) == 0)
            bitsW[(size_t)(b * Nn + r) * 64 + cj8 + (lane >> 3)] = w32;
    }
    __shared__ float sred[8][256];
    sred[w][4 * lane + 0] = s0;
    sred[w][4 * lane + 1] = s1;
    sred[w][4 * lane + 2] = s2;
    sred[w][4 * lane + 3] = s3;
    __syncthreads();
    if (threadIdx.x < 256) {
        int c = threadIdx.x;
        float v = 0.f;
#pragma unroll
        for (int k = 0; k < 8; ++k) v += sred[k][c];
        atomicAdd(&Dsum[b * Nn + j0 + c], v);
    }
}

// ------- k2b: per-column table cf4 = {f2, e^f2/D, e^(a f2)/D, 1/D}  +  rank-1 base C[b][o] = sum_j h[j][o]/D_j -------
// widened: grid (Bn, 128), 16 cols/block, 1024 blocks (was 256 = 1 block/CU, latency-exposed)
__global__ __launch_bounds__(256) void k2b_cols(
        const float* __restrict__ h, const float* __restrict__ Dsum,
        const float* __restrict__ f2,
        float4* __restrict__ cf4, float* __restrict__ C) {
    int b = blockIdx.x;
    int j0 = blockIdx.y * 16;
    int t = threadIdx.x;
    __shared__ float zl[16];
    __shared__ float sC[4][64];
    if (t < 16) {
        int j = j0 + t;
        float f2j = f2[b * Nn + j];
        float invD = 1.f / Dsum[b * Nn + j];
        cf4[b * Nn + j] = make_float4(f2j, __expf(f2j) * invD,
                                      __expf(ALPHA * f2j) * invD, invD);
        zl[t] = invD;
    }
    __syncthreads();
    int o = t & 63, cg = t >> 6;     // 4 col-groups x 4 cols
    const float* hbp = h + ((size_t)(b * Nn + j0 + cg * 4)) * Fn + o;
    float s = 0.f;
#pragma unroll
    for (int k = 0; k < 4; ++k) s = fmaf(zl[cg * 4 + k], hbp[(size_t)k * Fn], s);
    sC[cg][o] = s;
    __syncthreads();
    if (t < 64) {
        float v = sC[0][t] + sC[1][t] + sC[2][t] + sC[3][t];
        atomicAdd(&C[b * Fn + t], v);
    }
}

// ------- k3: one WAVE per output row, 4 rows/block, zero barriers -------
// Phase1: 64-lane bit decode -> LDS byte-offset list. Prefetch: first 8 h-gathers
// issued BEFORE phase 2 (depend only on offs) so their latency hides under the
// cf4 gathers. Phase2: fully-unrolled (<=3/lane) weights -> LDS. Phase3: peeled
// first group + unroll-16 gather, 4 accs. grid (Bn*Nn/4), block 256
__global__ __launch_bounds__(256) void k3_row(
        const unsigned* __restrict__ bits, const float4* __restrict__ cf4,
        const float* __restrict__ f1, const float* __restrict__ h,
        const float* __restrict__ C, const float* __restrict__ inp,
        const float* __restrict__ bias, float* __restrict__ out) {
    int w = threadIdx.x >> 6, lane = threadIdx.x & 63;
    int b = blockIdx.x >> 9;                      // uniform: 512 blocks per batch
    int i = ((blockIdx.x & 511) << 2) + w;
    int gr = (int)(blockIdx.x * 4) + w;           // = b*Nn + i
    __shared__ unsigned offs[4][CAPR];            // byte offsets j*256
    __shared__ float wvs[4][CAPR];

    // phase 1: decode this row's 64 bit-words (one per lane)
    unsigned word = bits[(size_t)gr * 64 + lane];
    unsigned pc = (unsigned)__popc(word);
    unsigned pre = pc;
#pragma unroll
    for (int off = 1; off < 64; off <<= 1) {
        unsigned v = (unsigned)__shfl_up((int)pre, off, 64);
        if (lane >= off) pre += v;
    }
    unsigned base = pre - pc;
    unsigned jb8 = ((unsigned)lane * 32u) << 8;
    while (word) {
        int k = __ffs(word) - 1;
        word &= word - 1;
        if (base < CAPR) offs[w][base] = jb8 + ((unsigned)k << 8);
        ++base;
    }
    unsigned cnt = (unsigned)__shfl((int)pre, 63, 64);
    if (cnt > CAPR) cnt = CAPR;

    float f1i = f1[gr];
    float ui = __expf(f1i), upi = __expf(ALPHA * f1i);
    const float4* cfp = cf4 + (size_t)b * Nn;
    const char* hbase = (const char*)(h + (size_t)b * Nn * Fn);
    unsigned lane4 = (unsigned)lane << 2;

    // prefetch the first 8 h-gathers (independent of phase 2's wvs)
    uint4 p0, p1;
    float g0, g1, g2, g3, g4, g5, g6, g7;
    bool pf = (cnt >= 8);
    if (pf) {
        p0 = *(const uint4*)&offs[w][0];
        p1 = *(const uint4*)&offs[w][4];
        g0 = *(const float*)(hbase + (p0.x + lane4));
        g1 = *(const float*)(hbase + (p0.y + lane4));
        g2 = *(const float*)(hbase + (p0.z + lane4));
        g3 = *(const float*)(hbase + (p0.w + lane4));
        g4 = *(const float*)(hbase + (p1.x + lane4));
        g5 = *(const float*)(hbase + (p1.y + lane4));
        g6 = *(const float*)(hbase + (p1.z + lane4));
        g7 = *(const float*)(hbase + (p1.w + lane4));
    }

    // epilogue operands issued early: latency hides under phase 2/3
    size_t g = (size_t)gr * Fn + lane;
    float inv = inp[g];
    float bvv = bias[(size_t)i * Fn + lane];
    float Cv  = C[b * Fn + lane];

    // phase 2: per-neighbor weights, lanes parallel over neighbors, <=3 per lane (CAPR=192)
    {
        unsigned ta = lane, tb = lane + 64u, tc = lane + 128u;
        bool va = ta < cnt, vb = tb < cnt, vc = tc < cnt;
        float4 ca, cb, cc;
        if (va) ca = cfp[offs[w][ta] >> 8];
        if (vb) cb = cfp[offs[w][tb] >> 8];
        if (vc) cc = cfp[offs[w][tc] >> 8];
        if (va) { float x = f1i + ca.x; wvs[w][ta] = (x > 0.f ? ui * ca.y : upi * ca.z) - ca.w; }
        if (vb) { float x = f1i + cb.x; wvs[w][tb] = (x > 0.f ? ui * cb.y : upi * cb.z) - cb.w; }
        if (vc) { float x = f1i + cc.x; wvs[w][tc] = (x > 0.f ? ui * cc.y : upi * cc.z) - cc.w; }
    }

    // phase 3: peeled prefetched group, then unroll-16 gather (16 loads in flight)
    float acc0 = 0.f, acc1 = 0.f, acc2 = 0.f, acc3 = 0.f;
    unsigned t = 0;
    if (pf) {
        float4 wa = *(const float4*)&wvs[w][0];
        float4 wb = *(const float4*)&wvs[w][4];
        acc0 = fmaf(wa.x, g0, acc0);
        acc1 = fmaf(wa.y, g1, acc1);
        acc2 = fmaf(wa.z, g2, acc2);
        acc3 = fmaf(wa.w, g3, acc3);
        acc0 = fmaf(wb.x, g4, acc0);
        acc1 = fmaf(wb.y, g5, acc1);
        acc2 = fmaf(wb.z, g6, acc2);
        acc3 = fmaf(wb.w, g7, acc3);
        t = 8;
    }
    for (; t + 16 <= cnt; t += 16) {
        uint4 oa = *(const uint4*)&offs[w][t];
        uint4 ob = *(const uint4*)&offs[w][t + 4];
        uint4 oc = *(const uint4*)&offs[w][t + 8];
        uint4 od = *(const uint4*)&offs[w][t + 12];
        float4 wa = *(const float4*)&wvs[w][t];
        float4 wb = *(const float4*)&wvs[w][t + 4];
        float4 wc = *(const float4*)&wvs[w][t + 8];
        float4 wd = *(const float4*)&wvs[w][t + 12];
        float h0 = *(const float*)(hbase + (oa.x + lane4));
        float h1 = *(const float*)(hbase + (oa.y + lane4));
        float h2 = *(const float*)(hbase + (oa.z + lane4));
        float h3 = *(const float*)(hbase + (oa.w + lane4));
        float h4 = *(const float*)(hbase + (ob.x + lane4));
        float h5 = *(const float*)(hbase + (ob.y + lane4));
        float h6 = *(const float*)(hbase + (ob.z + lane4));
        float h7 = *(const float*)(hbase + (ob.w + lane4));
        float h8 = *(const float*)(hbase + (oc.x + lane4));
        float h9 = *(const float*)(hbase + (oc.y + lane4));
        float hA = *(const float*)(hbase + (oc.z + lane4));
        float hB = *(const float*)(hbase + (oc.w + lane4));
        float hC = *(const float*)(hbase + (od.x + lane4));
        float hD = *(const float*)(hbase + (od.y + lane4));
        float hE = *(const float*)(hbase + (od.z + lane4));
        float hF = *(const float*)(hbase + (od.w + lane4));
        acc0 = fmaf(wa.x, h0, acc0);
        acc1 = fmaf(wa.y, h1, acc1);
        acc2 = fmaf(wa.z, h2, acc2);
        acc3 = fmaf(wa.w, h3, acc3);
        acc0 = fmaf(wb.x, h4, acc0);
        acc1 = fmaf(wb.y, h5, acc1);
        acc2 = fmaf(wb.z, h6, acc2);
        acc3 = fmaf(wb.w, h7, acc3);
        acc0 = fmaf(wc.x, h8, acc0);
        acc1 = fmaf(wc.y, h9, acc1);
        acc2 = fmaf(wc.z, hA, acc2);
        acc3 = fmaf(wc.w, hB, acc3);
        acc0 = fmaf(wd.x, hC, acc0);
        acc1 = fmaf(wd.y, hD, acc1);
        acc2 = fmaf(wd.z, hE, acc2);
        acc3 = fmaf(wd.w, hF, acc3);
    }
    for (; t + 4 <= cnt; t += 4) {
        uint4 oa = *(const uint4*)&offs[w][t];
        float4 wa = *(const float4*)&wvs[w][t];
        float h0 = *(const float*)(hbase + (oa.x + lane4));
        float h1 = *(const float*)(hbase + (oa.y + lane4));
        float h2 = *(const float*)(hbase + (oa.z + lane4));
        float h3 = *(const float*)(hbase + (oa.w + lane4));
        acc0 = fmaf(wa.x, h0, acc0);
        acc1 = fmaf(wa.y, h1, acc1);
        acc2 = fmaf(wa.z, h2, acc2);
        acc3 = fmaf(wa.w, h3, acc3);
    }
    for (; t < cnt; ++t) {
        float hv = *(const float*)(hbase + (offs[w][t] + lane4));
        acc0 = fmaf(wvs[w][t], hv, acc0);
    }
    float v = (acc0 + acc1) + (acc2 + acc3) + Cv;
    out[g] = elu(v + inv + bvv);
}

extern "C" void kernel_launch(void* const* d_in, const int* in_sizes, int n_in,
                              void* d_out, int out_size, void* d_ws, size_t ws_size,
                              hipStream_t stream) {
    const float* inp  = (const float*)d_in[0];
    const float* adj  = (const float*)d_in[1];
    const float* W    = (const float*)d_in[2];
    const float* a1   = (const float*)d_in[3];
    const float* a2   = (const float*)d_in[4];
    const float* bias = (const float*)d_in[5];
    float* out = (float*)d_out;

    // workspace layout (~8.5 MiB)
    char* ws = (char*)d_ws;
    unsigned* bitsW = (unsigned*)ws;                           // 8*2048*64*4 = 4,194,304
    float*  h     = (float*)(ws + 4194304);                    // 4,194,304
    float4* cf4   = (float4*)(ws + 8388608);                   //   262,144
    float*  f1    = (float*)(ws + 8650752);                    //    65,536
    float*  f2    = (float*)(ws + 8716288);                    //    65,536
    float*  Dsum  = (float*)(ws + 8781824);                    //    65,536 (zeroed in k1)
    float*  C     = (float*)(ws + 8847360);                    //     2,048 (zeroed in k1)

    k1_h_f<<<Bn * Nn / 16, 256, 0, stream>>>(inp, W, a1, a2, h, f1, f2, Dsum, C);
    k2a_bits<<<dim3(Bn, 8, 32), 512, 0, stream>>>(adj, f1, f2, Dsum, bitsW);
    k2b_cols<<<dim3(Bn, Nn / 16), 256, 0, stream>>>(h, Dsum, f2, cf4, C);
    k3_row<<<Bn * Nn / 4, 256, 0, stream>>>(bitsW, cf4, f1, h, C, inp, bias, out);
}